// Round 6
// baseline (363.365 us; speedup 1.0000x reference)
//
#include <hip/hip_runtime.h>
#include <math.h>

#define N_NODES 2048
#define NNE ((long)N_NODES * N_NODES)   // elems per channel matrix

// f16 two-term split: x ~= h + l (true residual). Three MFMA products
// (hh, lh, hl) into ONE fp32 accumulator; dropped l*l term ~2^-22 relative.
// Scale chain (all powers of 2, exact):
//   V0' = supd * 2^13
//   T0  = Hc@V0'  -> scaled by sT0[f] = 2^(10-ilogb(cn0[f])), cn0=sum_m|V0'|
//   T1  = Hb@T0'  -> scaled by sT1[f] = 2^(10-ilogb(cn1[f])), cn1=sum_j|T0'|
//   T2  = Ha@T1'  (fp32); out = d*(T2*2^(i0+i1-33)) + d^2*sup + b
// H matrices never materialized: gemm_mix_k mixes A->H on the fly.
// R5b (resubmit; R5 was an infra failure): B operand loaded global->register
//     (fragments, no LDS staging, no vmcnt drain at barriers); A reg-prefetch
//     1 chunk; LDS 40->8 KB; supd materialization dropped. launch_bounds
//     relaxed to (256) to avoid VGPR spill at the 128-reg/4-wave cap.
#define SUPD_SCALE 8192.0f

typedef _Float16 half4_t __attribute__((ext_vector_type(4)));
typedef _Float16 half8_t __attribute__((ext_vector_type(8)));
typedef float    floatx4 __attribute__((ext_vector_type(4)));

__device__ __forceinline__ float colscale_from(float cn) {
  return exp2f((float)(10 - ilogbf(fmaxf(cn, 1e-37f))));
}

// ---- softmax of the three 4x4 weight matrices + zero cn0/cn1 (1024 f) ----
__global__ void softmax3_zero_k(const float* __restrict__ w1,
                                const float* __restrict__ w2,
                                const float* __restrict__ w3,
                                float* __restrict__ fw,
                                float* __restrict__ cn) {
  int t = threadIdx.x;
  float4 z4 = {0.f, 0.f, 0.f, 0.f};
  ((float4*)cn)[t] = z4;                       // 256*4 = 1024 floats
  if (t < 12) {
    const float* src = (t < 4) ? w1 : (t < 8) ? w2 : w3;
    int r = t & 3;
    float v0 = src[r * 4 + 0], v1 = src[r * 4 + 1];
    float v2 = src[r * 4 + 2], v3 = src[r * 4 + 3];
    float m = fmaxf(fmaxf(v0, v1), fmaxf(v2, v3));
    float e0 = expf(v0 - m), e1 = expf(v1 - m), e2 = expf(v2 - m), e3 = expf(v3 - m);
    float inv = 1.0f / (e0 + e1 + e2 + e3);
    fw[t * 4 + 0] = e0 * inv; fw[t * 4 + 1] = e1 * inv;
    fw[t * 4 + 2] = e2 * inv; fw[t * 4 + 3] = e3 * inv;
  }
}

// ---------------- support = X @ gcn_w  [2048,256]@[256,128] ----------------
__global__ __launch_bounds__(128)
void support_k(const float* __restrict__ X, const float* __restrict__ W,
               float* __restrict__ sup) {
  __shared__ float Xs[256];
  const int t = threadIdx.x;
  const int m = blockIdx.x;
  Xs[t]       = X[(long)m * 256 + t];
  Xs[t + 128] = X[(long)m * 256 + t + 128];
  __syncthreads();
  float acc = 0.f;
  #pragma unroll 8
  for (int k = 0; k < 256; ++k) acc = fmaf(Xs[k], W[(long)k * 128 + t], acc);
  sup[(long)m * 128 + t] = acc;
}

// ---- rc[c][r] = sum_e fw3[c][e] * rowsum(A_e)[r] ----------
// One row per block; 4 waves split the j-range; mix folded before reduce.
__global__ __launch_bounds__(256)
void rc_from_A_k(const float* __restrict__ A, const float* __restrict__ fw,
                 float* __restrict__ rc) {
  __shared__ float red[4][4];
  const int r = blockIdx.x;
  const int w = threadIdx.x >> 6, lane = threadIdx.x & 63;
  float se[4];
  #pragma unroll
  for (int e = 0; e < 4; ++e) {
    const float4* row = (const float4*)(A + (long)e * NNE + (long)r * N_NODES);
    float s = 0.f;
    #pragma unroll
    for (int q = 0; q < 2; ++q) {
      float4 a = row[w * 128 + q * 64 + lane];
      s += (a.x + a.y) + (a.z + a.w);
    }
    se[e] = s;
  }
  float m[4];
  #pragma unroll
  for (int c = 0; c < 4; ++c)
    m[c] = fw[32 + c * 4 + 0] * se[0] + fw[32 + c * 4 + 1] * se[1] +
           fw[32 + c * 4 + 2] * se[2] + fw[32 + c * 4 + 3] * se[3];
  #pragma unroll
  for (int o = 32; o > 0; o >>= 1) {
    #pragma unroll
    for (int c = 0; c < 4; ++c) m[c] += __shfl_down(m[c], o, 64);
  }
  if (lane == 0) {
    #pragma unroll
    for (int c = 0; c < 4; ++c) red[w][c] = m[c];
  }
  __syncthreads();
  if (threadIdx.x < 4) {
    int c = threadIdx.x;
    rc[c * N_NODES + r] = (red[0][c] + red[1][c]) + (red[2][c] + red[3][c]);
  }
}

// -- vout[c][r] = sum_e fw[off+c*4+e] * (A_e @ vin[c])[r]  (fp32) ----------
// One row per block; 4 waves split j; vin read direct (32 KB, L2-hot).
__global__ __launch_bounds__(256)
void matvecA_k(const float* __restrict__ A, const float* __restrict__ fw, int off,
               const float* __restrict__ vin, float* __restrict__ vout) {
  __shared__ float red[4][4];
  const int r = blockIdx.x;
  const int w = threadIdx.x >> 6, lane = threadIdx.x & 63;
  float acc[4][4] = {{0.f}};
  #pragma unroll
  for (int q = 0; q < 2; ++q) {
    const int j4 = w * 128 + q * 64 + lane;
    float4 v0 = *(const float4*)&vin[0 * 2048 + j4 * 4];
    float4 v1 = *(const float4*)&vin[1 * 2048 + j4 * 4];
    float4 v2 = *(const float4*)&vin[2 * 2048 + j4 * 4];
    float4 v3 = *(const float4*)&vin[3 * 2048 + j4 * 4];
    #pragma unroll
    for (int e = 0; e < 4; ++e) {
      float4 a = *(const float4*)(A + (long)e * NNE + (long)r * N_NODES + j4 * 4);
      acc[e][0] += (a.x * v0.x + a.y * v0.y) + (a.z * v0.z + a.w * v0.w);
      acc[e][1] += (a.x * v1.x + a.y * v1.y) + (a.z * v1.z + a.w * v1.w);
      acc[e][2] += (a.x * v2.x + a.y * v2.y) + (a.z * v2.z + a.w * v2.w);
      acc[e][3] += (a.x * v3.x + a.y * v3.y) + (a.z * v3.z + a.w * v3.w);
    }
  }
  float m[4];
  #pragma unroll
  for (int c = 0; c < 4; ++c)
    m[c] = fw[off + c * 4 + 0] * acc[0][c] + fw[off + c * 4 + 1] * acc[1][c] +
           fw[off + c * 4 + 2] * acc[2][c] + fw[off + c * 4 + 3] * acc[3][c];
  #pragma unroll
  for (int o = 32; o > 0; o >>= 1) {
    #pragma unroll
    for (int c = 0; c < 4; ++c) m[c] += __shfl_down(m[c], o, 64);
  }
  if (lane == 0) {
    #pragma unroll
    for (int c = 0; c < 4; ++c) red[w][c] = m[c];
  }
  __syncthreads();
  if (threadIdx.x < 4) {
    int c = threadIdx.x;
    vout[c * N_NODES + r] = (red[0][c] + red[1][c]) + (red[2][c] + red[3][c]);
  }
}

// -- fused: dm = 1/sqrt(1+deg); dvec side output;
// -- VT[z][f][m] = split( dm*sup*2^13 ); cn0[z][f] += sum_m |val| ----------
__global__ __launch_bounds__(256)
void transposeV_k(const float* __restrict__ sup, const float* __restrict__ deg,
                  float* __restrict__ dvec,
                  _Float16* __restrict__ TH, _Float16* __restrict__ TL,
                  float* __restrict__ cn0) {
  __shared__ _Float16 sh[32][33], sl[32][33];
  __shared__ float red[8][32];
  const int t = threadIdx.x;
  const int z = blockIdx.z;
  const int m0 = blockIdx.x * 32, f0 = blockIdx.y * 32;
  const int r0 = t >> 5, col = t & 31;
  float part = 0.f;
  #pragma unroll
  for (int m = 0; m < 4; ++m) {
    const int row = m0 + r0 + 8 * m;
    float dm = 1.0f / sqrtf(1.0f + deg[(long)z * N_NODES + row]);
    float sv = sup[(long)row * 128 + f0 + col] * dm;
    if (blockIdx.y == 0 && col == 0) dvec[(long)z * N_NODES + row] = dm;
    float v = sv * SUPD_SCALE;
    _Float16 h = (_Float16)v;
    sh[r0 + 8 * m][col] = h;
    sl[r0 + 8 * m][col] = (_Float16)(v - (float)h);
    part += fabsf(v);
  }
  red[r0][col] = part;
  __syncthreads();
  if (t < 32) {
    float s = 0.f;
    #pragma unroll
    for (int q = 0; q < 8; ++q) s += red[q][t];
    atomicAdd(&cn0[(long)z * 128 + f0 + t], s);
  }
  const int rr = t >> 3, cq = (t & 7) * 4;
  half4_t oh, ol;
  #pragma unroll
  for (int d = 0; d < 4; ++d) { oh[d] = sh[cq + d][rr]; ol[d] = sl[cq + d][rr]; }
  long ob = (long)z * 128 * N_NODES + (long)(f0 + rr) * N_NODES + m0 + cq;
  *(half4_t*)(TH + ob) = oh;
  *(half4_t*)(TL + ob) = ol;
}

// ---- fused mix+GEMM: partials[kc][ch][i][f] = (sum_e fw[off+ch*4+e] A_e) @ B[ch]
// One channel per block. Flat grid 1024 = tile(64) + 64*ch(4) + 256*kc(4).
// B fragments loaded global->register (ping-pong, 1 chunk ahead): no LDS
// staging for B, so barriers drain only LDS (H tile) — B latency spans them.
// LDS = 8 KB (H dbuf only).
__global__ __launch_bounds__(256)
void gemm_mix_k(const float* __restrict__ A, const float* __restrict__ fw, int off,
                const _Float16* __restrict__ BH, const _Float16* __restrict__ BL,
                float* __restrict__ C) {
  __shared__ __align__(16) _Float16 Hs[2][2][1024];   // [buf][hl][32r x 32k swz]

  const int t = threadIdx.x;
  const int lane = t & 63;
  const int w = t >> 6;
  const int bid = blockIdx.x;
  const int tile = bid & 63;
  const int ch = (bid >> 6) & 3;
  const int kc = bid >> 8;              // 0..3
  const int i0 = tile * 32;
  const long koff = (long)kc * 512;

  float wv[4];
  #pragma unroll
  for (int e = 0; e < 4; ++e) wv[e] = fw[off + ch * 4 + e];

  // A per-thread source: row rr, k-cols k4..k4+3, all 4 e
  const int rr = t >> 3;                // 0..31
  const int k4 = (t & 7) * 4;           // 0..28
  const float* gA = A + (long)(i0 + rr) * N_NODES + koff + k4;
  // H store offset, k-group swizzle p = (g + (row>>1)) & 3
  const int hoff = rr * 32 + (((k4 >> 3) + (rr >> 1)) & 3) * 8 + (k4 & 7);

  // MFMA fragment offsets
  const int wm = w >> 1, wn = w & 1;
  const int fr = lane & 15;
  const int fq = lane >> 4;
  const int fkz = ((fq + (fr >> 1)) & 3) * 8;
  const int aoff = (wm * 16 + fr) * 32 + fkz;

  // B fragment global base: row f = ch*128 + wn*64 + nt*16 + fr, k = fq*8
  const long bbase = ((long)(ch * 128 + wn * 64 + fr)) * N_NODES + koff + fq * 8;
  const _Float16* gBH = BH + bbase;
  const _Float16* gBL = BL + bbase;

  floatx4 acc[4];
  #pragma unroll
  for (int j = 0; j < 4; ++j) {
    floatx4 zz4 = {0.f, 0.f, 0.f, 0.f};
    acc[j] = zz4;
  }

  float4 aA[4], aB[4];
  half8_t b0h[4], b0l[4], b1h[4], b1l[4];

  auto loadA = [&](float4* av, int kt) {
    const float* g = gA + kt * 32;
    av[0] = *(const float4*)(g);
    av[1] = *(const float4*)(g + NNE);
    av[2] = *(const float4*)(g + 2 * NNE);
    av[3] = *(const float4*)(g + 3 * NNE);
  };
  auto loadB = [&](half8_t* bh, half8_t* bl, int kt) {
    #pragma unroll
    for (int nt = 0; nt < 4; ++nt) {
      bh[nt] = *(const half8_t*)(gBH + (long)nt * 16 * N_NODES + kt * 32);
      bl[nt] = *(const half8_t*)(gBL + (long)nt * 16 * N_NODES + kt * 32);
    }
  };
  auto mixStore = [&](const float4* av, int pb) {
    half4_t h, l;
    #pragma unroll
    for (int d = 0; d < 4; ++d) {
      float o = wv[0] * ((const float*)&av[0])[d] + wv[1] * ((const float*)&av[1])[d] +
                wv[2] * ((const float*)&av[2])[d] + wv[3] * ((const float*)&av[3])[d];
      _Float16 hh = (_Float16)o;
      h[d] = hh; l[d] = (_Float16)(o - (float)hh);
    }
    *(half4_t*)&Hs[pb][0][hoff] = h;
    *(half4_t*)&Hs[pb][1][hoff] = l;
  };
  auto domfma = [&](int pb, const half8_t* bh, const half8_t* bl) {
    half8_t ah = *(const half8_t*)&Hs[pb][0][aoff];
    half8_t al = *(const half8_t*)&Hs[pb][1][aoff];
    #pragma unroll
    for (int nt = 0; nt < 4; ++nt) {
      acc[nt] = __builtin_amdgcn_mfma_f32_16x16x32_f16(ah, bh[nt], acc[nt], 0, 0, 0);
      acc[nt] = __builtin_amdgcn_mfma_f32_16x16x32_f16(al, bh[nt], acc[nt], 0, 0, 0);
      acc[nt] = __builtin_amdgcn_mfma_f32_16x16x32_f16(ah, bl[nt], acc[nt], 0, 0, 0);
    }
  };

  // prologue: chunk0 -> Hs[0]/b0, chunk1 -> aB/b1 (in flight)
  loadA(aA, 0); loadB(b0h, b0l, 0);
  mixStore(aA, 0);
  loadA(aB, 1); loadB(b1h, b1l, 1);
  __syncthreads();

  for (int kt = 0; kt < 16; kt += 2) {
    const bool more = (kt + 2 < 16);
    if (more) loadA(aA, kt + 2);
    domfma(0, b0h, b0l);                 // chunk kt
    if (more) loadB(b0h, b0l, kt + 2);
    mixStore(aB, 1);                     // chunk kt+1 -> Hs[1]
    __syncthreads();
    if (more) loadA(aB, kt + 3);
    domfma(1, b1h, b1l);                 // chunk kt+1
    if (more) {
      loadB(b1h, b1l, kt + 3);
      mixStore(aA, 0);                   // chunk kt+2 -> Hs[0]
    }
    __syncthreads();
  }

  const int er = fq * 4;
  const int ec = lane & 15;
  float* Cb = C + ((long)(kc * 4 + ch) * N_NODES + i0 + wm * 16) * 128;
  #pragma unroll
  for (int nt = 0; nt < 4; ++nt) {
    const int f = wn * 64 + nt * 16 + ec;
    #pragma unroll
    for (int r = 0; r < 4; ++r)
      Cb[(long)(er + r) * 128 + f] = acc[nt][r];
  }
}

// -- T'[z][f][j] = split( (sum_parts P[pp][z][j][f]) * s(cn_in[z][f]) ) -----
__global__ __launch_bounds__(256)
void combineT_k(const float* __restrict__ P, int parts,
                const float* __restrict__ cn_in, float* __restrict__ cn_out,
                _Float16* __restrict__ TH, _Float16* __restrict__ TL) {
  __shared__ _Float16 sh[32][33], sl[32][33];
  __shared__ float red[8][32];
  const int t = threadIdx.x;
  const int z = blockIdx.z;
  const int j0 = blockIdx.x * 32, f0 = blockIdx.y * 32;
  const int r0 = t >> 5, col = t & 31;
  const float s = colscale_from(cn_in[(long)z * 128 + f0 + col]);
  const long step = 4L * N_NODES * 128;
  float part = 0.f;
  #pragma unroll
  for (int m = 0; m < 4; ++m) {
    long idx = ((long)z * N_NODES + j0 + r0 + 8 * m) * 128 + f0 + col;
    float v = (P[idx] + P[idx + step]) + (P[idx + 2 * step] + P[idx + 3 * step]);
    v *= s;
    _Float16 h = (_Float16)v;
    sh[r0 + 8 * m][col] = h;
    sl[r0 + 8 * m][col] = (_Float16)(v - (float)h);
    part += fabsf(v);
  }
  if (cn_out) red[r0][col] = part;
  __syncthreads();
  if (cn_out && t < 32) {
    float ss = 0.f;
    #pragma unroll
    for (int q = 0; q < 8; ++q) ss += red[q][t];
    atomicAdd(&cn_out[(long)z * 128 + f0 + t], ss);
  }
  const int rr = t >> 3, cq = (t & 7) * 4;
  half4_t oh, ol;
  #pragma unroll
  for (int d = 0; d < 4; ++d) { oh[d] = sh[cq + d][rr]; ol[d] = sl[cq + d][rr]; }
  long ob = (long)z * 128 * N_NODES + (long)(f0 + rr) * N_NODES + j0 + cq;
  *(half4_t*)(TH + ob) = oh;
  *(half4_t*)(TL + ob) = ol;
}

// --- out[i][c*128+f] = relu( d*(T2sum*2^(i0+i1-33)) + d^2*sup + b ) --------
__global__ __launch_bounds__(256)
void final_k(const float4* __restrict__ T2, const float4* __restrict__ sup4,
             const float* __restrict__ dvec, const float* __restrict__ cn0,
             const float* __restrict__ cn1, const float* __restrict__ bias,
             float* __restrict__ out) {
  const int t = threadIdx.x;
  const int z = blockIdx.y;
  const int idx = blockIdx.x * 256 + t;
  const int i = idx >> 5;
  const int fq = (idx & 31) * 4;
  const long step4 = 4L * N_NODES * 32;
  long b4 = (long)z * N_NODES * 32 + idx;
  float4 s0 = T2[b4];
  float4 s1 = T2[b4 + step4];
  float4 s2 = T2[b4 + 2 * step4];
  float4 s3 = T2[b4 + 3 * step4];
  float4 su = sup4[idx];                     // sup[i][fq..fq+3]
  const float dn = dvec[(long)z * N_NODES + i];
  const float dn2 = dn * dn;
  float inv[4];
  #pragma unroll
  for (int d = 0; d < 4; ++d) {
    int i0 = ilogbf(fmaxf(cn0[(long)z * 128 + fq + d], 1e-37f));
    int i1 = ilogbf(fmaxf(cn1[(long)z * 128 + fq + d], 1e-37f));
    inv[d] = exp2f((float)(i0 + i1 - 33)) * dn;
  }
  float4 o;
  o.x = fmaxf(((s0.x + s1.x) + (s2.x + s3.x)) * inv[0] + dn2 * su.x + bias[fq + 0], 0.f);
  o.y = fmaxf(((s0.y + s1.y) + (s2.y + s3.y)) * inv[1] + dn2 * su.y + bias[fq + 1], 0.f);
  o.z = fmaxf(((s0.z + s1.z) + (s2.z + s3.z)) * inv[2] + dn2 * su.z + bias[fq + 2], 0.f);
  o.w = fmaxf(((s0.w + s1.w) + (s2.w + s3.w)) * inv[3] + dn2 * su.w + bias[fq + 3], 0.f);
  *(float4*)(out + (long)i * 512 + z * 128 + fq) = o;
}

extern "C" void kernel_launch(void* const* d_in, const int* in_sizes, int n_in,
                              void* d_out, int out_size, void* d_ws, size_t ws_size,
                              hipStream_t stream) {
  const float* A  = (const float*)d_in[0];
  const float* X  = (const float*)d_in[1];
  const float* w1 = (const float*)d_in[2];
  const float* w2 = (const float*)d_in[3];
  const float* w3 = (const float*)d_in[4];
  const float* gw = (const float*)d_in[5];
  const float* gb = (const float*)d_in[6];
  float* out = (float*)d_out;

  // ---- workspace layout (floats first, then f16 arena; all 16B aligned) ----
  float* ws   = (float*)d_ws;
  float* fw   = ws;                         // 64
  float* rc   = fw + 64;                    // 4*2048
  float* v1   = rc + 4 * N_NODES;           // 4*2048
  float* deg  = v1 + 4 * N_NODES;           // 4*2048
  float* dvec = deg + 4 * N_NODES;          // 4*2048
  float* sup  = dvec + 4 * N_NODES;         // 2048*128
  float* cn0  = sup + (long)N_NODES * 128;  // 512
  float* cn1  = cn0 + 512;                  // 512
  float* Mtmp = cn1 + 512;                  // [4kc][4ch][2048][128]
  _Float16* arena = (_Float16*)(Mtmp + 16L * N_NODES * 128);
  _Float16* VTH = arena;                    // [4][128][2048]
  _Float16* VTL = VTH + 4L * 128 * N_NODES;
  _Float16* T0H = VTL + 4L * 128 * N_NODES;
  _Float16* T0L = T0H + 4L * 128 * N_NODES;
  _Float16* T1H = T0L + 4L * 128 * N_NODES;
  _Float16* T1L = T1H + 4L * 128 * N_NODES;

  // ---- prework ----
  softmax3_zero_k<<<1, 256, 0, stream>>>(w1, w2, w3, fw, cn0);   // zeroes cn0+cn1
  support_k<<<N_NODES, 128, 0, stream>>>(X, gw, sup);
  // deg chain: rc = fw3-mix of rowsum(A_e); v1 = Hb@rc; deg = Ha@v1
  rc_from_A_k<<<N_NODES, 256, 0, stream>>>(A, fw, rc);
  matvecA_k<<<N_NODES, 256, 0, stream>>>(A, fw, 16, rc, v1);
  matvecA_k<<<N_NODES, 256, 0, stream>>>(A, fw, 0, v1, deg);
  // VT = (d .* sup * 2^13)^T split ; cn0 col 1-norms ; dvec
  transposeV_k<<<dim3(64, 4, 4), 256, 0, stream>>>(sup, deg, dvec,
                                                   VTH, VTL, cn0);
  // T0 = Hc @ VT   (mix-on-the-fly from A, fw offset 32)
  gemm_mix_k<<<1024, 256, 0, stream>>>(A, fw, 32, VTH, VTL, Mtmp);
  combineT_k<<<dim3(64, 4, 4), 256, 0, stream>>>(Mtmp, 4, cn0, cn1, T0H, T0L);
  // T1 = Hb @ T0'  (fw offset 16)
  gemm_mix_k<<<1024, 256, 0, stream>>>(A, fw, 16, T0H, T0L, Mtmp);
  combineT_k<<<dim3(64, 4, 4), 256, 0, stream>>>(Mtmp, 4, cn1, nullptr, T1H, T1L);
  // T2 = Ha @ T1'  (fw offset 0, fp32 partials)
  gemm_mix_k<<<1024, 256, 0, stream>>>(A, fw, 0, T1H, T1L, Mtmp);
  // out = relu( d*(T2*inv) + d^2*sup + b )
  final_k<<<dim3(256, 4), 256, 0, stream>>>((const float4*)Mtmp,
                                            (const float4*)sup, dvec,
                                            cn0, cn1, gb, out);
}

// Round 7
// 267.663 us; speedup vs baseline: 1.3575x; 1.3575x over previous
//
#include <hip/hip_runtime.h>
#include <math.h>

#define N_NODES 2048
#define NNE ((long)N_NODES * N_NODES)   // elems per channel matrix

// f16 two-term split: x ~= h + l (true residual). Three MFMA products
// (hh, lh, hl) into ONE fp32 accumulator; dropped l*l term ~2^-22 relative.
// Scale chain (all powers of 2, exact):
//   V0' = supd * 2^13
//   T0  = Hc@V0'  -> scaled by sT0[f] = 2^(10-ilogb(cn0[f])), cn0=sum_m|V0'|
//   T1  = Hb@T0'  -> scaled by sT1[f] = 2^(10-ilogb(cn1[f])), cn1=sum_j|T0'|
//   T2  = Ha@T1'  (fp32); out = d*(T2*2^(i0+i1-33)) + d^2*sup + b
// H matrices never materialized: gemm_mix_k mixes A->H on the fly.
// R7: counted-vmcnt pipeline (T4). B via global_load_lds into 3 rotating
//     LDS buffers staged 2 chunks ahead; barriers wait vmcnt(8) (newest 8
//     VMEM ops stay in flight) + lgkmcnt(0), raw s_barrier. A in 3 named
//     register sets loaded 3 chunks ahead. 16 segments statically unrolled.
#define SUPD_SCALE 8192.0f

typedef _Float16 half4_t __attribute__((ext_vector_type(4)));
typedef _Float16 half8_t __attribute__((ext_vector_type(8)));
typedef float    floatx4 __attribute__((ext_vector_type(4)));

__device__ __forceinline__ void async_cp16(const void* g, void* l) {
  __builtin_amdgcn_global_load_lds((const __attribute__((address_space(1))) void*)g,
                                   (__attribute__((address_space(3))) void*)l,
                                   16, 0, 0);
}

__device__ __forceinline__ float colscale_from(float cn) {
  return exp2f((float)(10 - ilogbf(fmaxf(cn, 1e-37f))));
}

// ---- softmax of the three 4x4 weight matrices + zero cn0/cn1 (1024 f) ----
__global__ void softmax3_zero_k(const float* __restrict__ w1,
                                const float* __restrict__ w2,
                                const float* __restrict__ w3,
                                float* __restrict__ fw,
                                float* __restrict__ cn) {
  int t = threadIdx.x;
  float4 z4 = {0.f, 0.f, 0.f, 0.f};
  ((float4*)cn)[t] = z4;                       // 256*4 = 1024 floats
  if (t < 12) {
    const float* src = (t < 4) ? w1 : (t < 8) ? w2 : w3;
    int r = t & 3;
    float v0 = src[r * 4 + 0], v1 = src[r * 4 + 1];
    float v2 = src[r * 4 + 2], v3 = src[r * 4 + 3];
    float m = fmaxf(fmaxf(v0, v1), fmaxf(v2, v3));
    float e0 = expf(v0 - m), e1 = expf(v1 - m), e2 = expf(v2 - m), e3 = expf(v3 - m);
    float inv = 1.0f / (e0 + e1 + e2 + e3);
    fw[t * 4 + 0] = e0 * inv; fw[t * 4 + 1] = e1 * inv;
    fw[t * 4 + 2] = e2 * inv; fw[t * 4 + 3] = e3 * inv;
  }
}

// ---------------- support = X @ gcn_w  [2048,256]@[256,128] ----------------
__global__ __launch_bounds__(128)
void support_k(const float* __restrict__ X, const float* __restrict__ W,
               float* __restrict__ sup) {
  __shared__ float Xs[256];
  const int t = threadIdx.x;
  const int m = blockIdx.x;
  Xs[t]       = X[(long)m * 256 + t];
  Xs[t + 128] = X[(long)m * 256 + t + 128];
  __syncthreads();
  float acc = 0.f;
  #pragma unroll 8
  for (int k = 0; k < 256; ++k) acc = fmaf(Xs[k], W[(long)k * 128 + t], acc);
  sup[(long)m * 128 + t] = acc;
}

// ---- rc[c][r] = sum_e fw3[c][e] * rowsum(A_e)[r] ----------
__global__ __launch_bounds__(256)
void rc_from_A_k(const float* __restrict__ A, const float* __restrict__ fw,
                 float* __restrict__ rc) {
  __shared__ float red[4][4];
  const int r = blockIdx.x;
  const int w = threadIdx.x >> 6, lane = threadIdx.x & 63;
  float se[4];
  #pragma unroll
  for (int e = 0; e < 4; ++e) {
    const float4* row = (const float4*)(A + (long)e * NNE + (long)r * N_NODES);
    float s = 0.f;
    #pragma unroll
    for (int q = 0; q < 2; ++q) {
      float4 a = row[w * 128 + q * 64 + lane];
      s += (a.x + a.y) + (a.z + a.w);
    }
    se[e] = s;
  }
  float m[4];
  #pragma unroll
  for (int c = 0; c < 4; ++c)
    m[c] = fw[32 + c * 4 + 0] * se[0] + fw[32 + c * 4 + 1] * se[1] +
           fw[32 + c * 4 + 2] * se[2] + fw[32 + c * 4 + 3] * se[3];
  #pragma unroll
  for (int o = 32; o > 0; o >>= 1) {
    #pragma unroll
    for (int c = 0; c < 4; ++c) m[c] += __shfl_down(m[c], o, 64);
  }
  if (lane == 0) {
    #pragma unroll
    for (int c = 0; c < 4; ++c) red[w][c] = m[c];
  }
  __syncthreads();
  if (threadIdx.x < 4) {
    int c = threadIdx.x;
    rc[c * N_NODES + r] = (red[0][c] + red[1][c]) + (red[2][c] + red[3][c]);
  }
}

// -- vout[c][r] = sum_e fw[off+c*4+e] * (A_e @ vin[c])[r]  (fp32) ----------
__global__ __launch_bounds__(256)
void matvecA_k(const float* __restrict__ A, const float* __restrict__ fw, int off,
               const float* __restrict__ vin, float* __restrict__ vout) {
  __shared__ float red[4][4];
  const int r = blockIdx.x;
  const int w = threadIdx.x >> 6, lane = threadIdx.x & 63;
  float acc[4][4] = {{0.f}};
  #pragma unroll
  for (int q = 0; q < 2; ++q) {
    const int j4 = w * 128 + q * 64 + lane;
    float4 v0 = *(const float4*)&vin[0 * 2048 + j4 * 4];
    float4 v1 = *(const float4*)&vin[1 * 2048 + j4 * 4];
    float4 v2 = *(const float4*)&vin[2 * 2048 + j4 * 4];
    float4 v3 = *(const float4*)&vin[3 * 2048 + j4 * 4];
    #pragma unroll
    for (int e = 0; e < 4; ++e) {
      float4 a = *(const float4*)(A + (long)e * NNE + (long)r * N_NODES + j4 * 4);
      acc[e][0] += (a.x * v0.x + a.y * v0.y) + (a.z * v0.z + a.w * v0.w);
      acc[e][1] += (a.x * v1.x + a.y * v1.y) + (a.z * v1.z + a.w * v1.w);
      acc[e][2] += (a.x * v2.x + a.y * v2.y) + (a.z * v2.z + a.w * v2.w);
      acc[e][3] += (a.x * v3.x + a.y * v3.y) + (a.z * v3.z + a.w * v3.w);
    }
  }
  float m[4];
  #pragma unroll
  for (int c = 0; c < 4; ++c)
    m[c] = fw[off + c * 4 + 0] * acc[0][c] + fw[off + c * 4 + 1] * acc[1][c] +
           fw[off + c * 4 + 2] * acc[2][c] + fw[off + c * 4 + 3] * acc[3][c];
  #pragma unroll
  for (int o = 32; o > 0; o >>= 1) {
    #pragma unroll
    for (int c = 0; c < 4; ++c) m[c] += __shfl_down(m[c], o, 64);
  }
  if (lane == 0) {
    #pragma unroll
    for (int c = 0; c < 4; ++c) red[w][c] = m[c];
  }
  __syncthreads();
  if (threadIdx.x < 4) {
    int c = threadIdx.x;
    vout[c * N_NODES + r] = (red[0][c] + red[1][c]) + (red[2][c] + red[3][c]);
  }
}

// -- fused: dm = 1/sqrt(1+deg); dvec side output;
// -- VT[z][f][m] = split( dm*sup*2^13 ); cn0[z][f] += sum_m |val| ----------
__global__ __launch_bounds__(256)
void transposeV_k(const float* __restrict__ sup, const float* __restrict__ deg,
                  float* __restrict__ dvec,
                  _Float16* __restrict__ TH, _Float16* __restrict__ TL,
                  float* __restrict__ cn0) {
  __shared__ _Float16 sh[32][33], sl[32][33];
  __shared__ float red[8][32];
  const int t = threadIdx.x;
  const int z = blockIdx.z;
  const int m0 = blockIdx.x * 32, f0 = blockIdx.y * 32;
  const int r0 = t >> 5, col = t & 31;
  float part = 0.f;
  #pragma unroll
  for (int m = 0; m < 4; ++m) {
    const int row = m0 + r0 + 8 * m;
    float dm = 1.0f / sqrtf(1.0f + deg[(long)z * N_NODES + row]);
    float sv = sup[(long)row * 128 + f0 + col] * dm;
    if (blockIdx.y == 0 && col == 0) dvec[(long)z * N_NODES + row] = dm;
    float v = sv * SUPD_SCALE;
    _Float16 h = (_Float16)v;
    sh[r0 + 8 * m][col] = h;
    sl[r0 + 8 * m][col] = (_Float16)(v - (float)h);
    part += fabsf(v);
  }
  red[r0][col] = part;
  __syncthreads();
  if (t < 32) {
    float s = 0.f;
    #pragma unroll
    for (int q = 0; q < 8; ++q) s += red[q][t];
    atomicAdd(&cn0[(long)z * 128 + f0 + t], s);
  }
  const int rr = t >> 3, cq = (t & 7) * 4;
  half4_t oh, ol;
  #pragma unroll
  for (int d = 0; d < 4; ++d) { oh[d] = sh[cq + d][rr]; ol[d] = sl[cq + d][rr]; }
  long ob = (long)z * 128 * N_NODES + (long)(f0 + rr) * N_NODES + m0 + cq;
  *(half4_t*)(TH + ob) = oh;
  *(half4_t*)(TL + ob) = ol;
}

// ---- fused mix+GEMM: partials[kc][ch][i][f] = (sum_e fw[off+ch*4+e] A_e) @ B[ch]
// One channel per block. Flat grid 1024 = tile(64) + 64*ch(4) + 256*kc(4).
// Counted-vmcnt pipeline: B staged 2 chunks ahead via global_load_lds into 3
// rotating LDS buffers; barrier = s_waitcnt vmcnt(8) lgkmcnt(0) + raw
// s_barrier (the newest 8 VMEM ops — next-next chunk's A+B — stay in
// flight). A loaded 3 chunks ahead into 3 named register sets. H mixed in
// regs, ds_written to a double buffer (lgkm-only at barrier).
__global__ __launch_bounds__(256, 2)
void gemm_mix_k(const float* __restrict__ A, const float* __restrict__ fw, int off,
                const _Float16* __restrict__ BH, const _Float16* __restrict__ BL,
                float* __restrict__ C) {
  __shared__ __align__(16) _Float16 BsArr[3 * 8192];  // 3 bufs x [hl][128f x 32k]
  __shared__ __align__(16) _Float16 HsArr[2 * 2048];  // 2 bufs x [hl][32r x 32k]

  const int t = threadIdx.x;
  const int lane = t & 63;
  const int w = t >> 6;
  const int bid = blockIdx.x;
  const int tile = bid & 63;
  const int ch = (bid >> 6) & 3;
  const int kc = bid >> 8;              // 0..3
  const int i0 = tile * 32;
  const long koff = (long)kc * 512;

  float wv[4];
  #pragma unroll
  for (int e = 0; e < 4; ++e) wv[e] = fw[off + ch * 4 + e];

  // A per-thread source: row rr, k-cols k4..k4+3, all 4 e
  const int rr = t >> 3;                // 0..31
  const int k4 = (t & 7) * 4;           // 0..28
  const float* gA = A + (long)(i0 + rr) * N_NODES + koff + k4;
  // H store offset, k-group swizzle p = (g + (row>>1)) & 3
  const int hoff = rr * 32 + (((k4 >> 3) + (rr >> 1)) & 3) * 8 + (k4 & 7);

  // B staging: wave w -> plane hls=w>>1 (0=H,1=L), rows half*64..; 4 cp16/chunk
  const int hls = w >> 1;
  const int half = w & 1;
  const int kc_st = (((lane & 3) - ((lane >> 3) & 3)) & 3) * 8;
  const _Float16* gB = (hls ? BL : BH)
                     + ((long)ch * 128 + half * 64 + (lane >> 2)) * (long)N_NODES
                     + koff + kc_st;

  // MFMA fragment offsets
  const int wm = w >> 1, wn = w & 1;
  const int fr = lane & 15;
  const int fq = lane >> 4;
  const int fkz = ((fq + (fr >> 1)) & 3) * 8;
  const int aoff = (wm * 16 + fr) * 32 + fkz;

  floatx4 acc[4];
  #pragma unroll
  for (int j = 0; j < 4; ++j) {
    floatx4 zz4 = {0.f, 0.f, 0.f, 0.f};
    acc[j] = zz4;
  }

  float4 sA[4], sB[4], sC[4];           // 3 named A register sets (no dyn idx)

  auto loadA = [&](float4* av, int kt) {
    const float* g = gA + kt * 32;
    av[0] = *(const float4*)(g);
    av[1] = *(const float4*)(g + NNE);
    av[2] = *(const float4*)(g + 2 * NNE);
    av[3] = *(const float4*)(g + 3 * NNE);
  };
  auto stageB = [&](int buf, int kt) {   // buf, kt compile-time at all sites
    _Float16* lb = BsArr + buf * 8192 + hls * 4096 + half * 2048;
    const _Float16* g = gB + kt * 32;
    #pragma unroll
    for (int q = 0; q < 4; ++q)
      async_cp16(g + (long)q * (16L * N_NODES), lb + q * 512 + lane * 8);
  };
  auto mixStore = [&](const float4* av, int hb) {
    half4_t h, l;
    #pragma unroll
    for (int d = 0; d < 4; ++d) {
      float o = wv[0] * ((const float*)&av[0])[d] + wv[1] * ((const float*)&av[1])[d] +
                wv[2] * ((const float*)&av[2])[d] + wv[3] * ((const float*)&av[3])[d];
      _Float16 hh = (_Float16)o;
      h[d] = hh; l[d] = (_Float16)(o - (float)hh);
    }
    *(half4_t*)&HsArr[hb * 2048 + hoff] = h;
    *(half4_t*)&HsArr[hb * 2048 + 1024 + hoff] = l;
  };
  auto domfma = [&](int buf, int hb) {
    half8_t ah = *(const half8_t*)&HsArr[hb * 2048 + aoff];
    half8_t al = *(const half8_t*)&HsArr[hb * 2048 + 1024 + aoff];
    const _Float16* bb = BsArr + buf * 8192;
    #pragma unroll
    for (int nt = 0; nt < 4; ++nt) {
      const int bo = (wn * 64 + nt * 16 + fr) * 32 + fkz;
      half8_t bh = *(const half8_t*)&bb[bo];
      half8_t bl = *(const half8_t*)&bb[4096 + bo];
      acc[nt] = __builtin_amdgcn_mfma_f32_16x16x32_f16(ah, bh, acc[nt], 0, 0, 0);
      acc[nt] = __builtin_amdgcn_mfma_f32_16x16x32_f16(al, bh, acc[nt], 0, 0, 0);
      acc[nt] = __builtin_amdgcn_mfma_f32_16x16x32_f16(ah, bl, acc[nt], 0, 0, 0);
    }
  };

#define SB0 __builtin_amdgcn_sched_barrier(0)
// steady barrier: keep newest 8 VMEM ops (next-next chunk's A+B) in flight
#define BAR_V8  do { SB0; asm volatile("s_waitcnt vmcnt(8) lgkmcnt(0)" ::: "memory"); \
                     SB0; __builtin_amdgcn_s_barrier(); SB0; } while (0)
#define BAR_V4  do { SB0; asm volatile("s_waitcnt vmcnt(4) lgkmcnt(0)" ::: "memory"); \
                     SB0; __builtin_amdgcn_s_barrier(); SB0; } while (0)

  // SEGMENT(KT, PA=A-load target set (kt%3), PM=mix source set ((kt+1)%3),
  //         BUFS=(kt+2)%3, BUFM=kt%3)
#define SEGMENT(KT, PA, PM, BUFS, BUFM)                                       \
  do {                                                                        \
    if ((KT) + 3 < 16) loadA(PA, (KT) + 3);                                   \
    if ((KT) + 2 < 16) stageB(BUFS, (KT) + 2);                                \
    domfma(BUFM, (KT) & 1);                                                   \
    if ((KT) + 1 < 16) mixStore(PM, ((KT) + 1) & 1);                          \
    if ((KT) <= 12)      BAR_V8;                                              \
    else if ((KT) == 13) BAR_V4;                                              \
    else if ((KT) == 14) __syncthreads();                                     \
  } while (0)

  // prologue: A(0..2) -> sA/sB/sC; B chunks 0,1 -> bufs 0,1; H(0) -> Hs[0]
  loadA(sA, 0); loadA(sB, 1); loadA(sC, 2);
  stageB(0, 0); stageB(1, 1);
  mixStore(sA, 0);
  BAR_V4;   // drains chunk0's cp16 (+A1,A2); chunk1's 4 cp16 stay in flight

  SEGMENT(0,  sA, sB, 2, 0);
  SEGMENT(1,  sB, sC, 0, 1);
  SEGMENT(2,  sC, sA, 1, 2);
  SEGMENT(3,  sA, sB, 2, 0);
  SEGMENT(4,  sB, sC, 0, 1);
  SEGMENT(5,  sC, sA, 1, 2);
  SEGMENT(6,  sA, sB, 2, 0);
  SEGMENT(7,  sB, sC, 0, 1);
  SEGMENT(8,  sC, sA, 1, 2);
  SEGMENT(9,  sA, sB, 2, 0);
  SEGMENT(10, sB, sC, 0, 1);
  SEGMENT(11, sC, sA, 1, 2);
  SEGMENT(12, sA, sB, 2, 0);
  SEGMENT(13, sB, sC, 0, 1);
  SEGMENT(14, sC, sA, 1, 2);
  SEGMENT(15, sA, sB, 2, 0);

#undef SEGMENT
#undef BAR_V8
#undef BAR_V4
#undef SB0

  const int er = fq * 4;
  const int ec = lane & 15;
  float* Cb = C + ((long)(kc * 4 + ch) * N_NODES + i0 + wm * 16) * 128;
  #pragma unroll
  for (int nt = 0; nt < 4; ++nt) {
    const int f = wn * 64 + nt * 16 + ec;
    #pragma unroll
    for (int r = 0; r < 4; ++r)
      Cb[(long)(er + r) * 128 + f] = acc[nt][r];
  }
}

// -- T'[z][f][j] = split( (sum_parts P[pp][z][j][f]) * s(cn_in[z][f]) ) -----
__global__ __launch_bounds__(256)
void combineT_k(const float* __restrict__ P, int parts,
                const float* __restrict__ cn_in, float* __restrict__ cn_out,
                _Float16* __restrict__ TH, _Float16* __restrict__ TL) {
  __shared__ _Float16 sh[32][33], sl[32][33];
  __shared__ float red[8][32];
  const int t = threadIdx.x;
  const int z = blockIdx.z;
  const int j0 = blockIdx.x * 32, f0 = blockIdx.y * 32;
  const int r0 = t >> 5, col = t & 31;
  const float s = colscale_from(cn_in[(long)z * 128 + f0 + col]);
  const long step = 4L * N_NODES * 128;
  float part = 0.f;
  #pragma unroll
  for (int m = 0; m < 4; ++m) {
    long idx = ((long)z * N_NODES + j0 + r0 + 8 * m) * 128 + f0 + col;
    float v = (P[idx] + P[idx + step]) + (P[idx + 2 * step] + P[idx + 3 * step]);
    v *= s;
    _Float16 h = (_Float16)v;
    sh[r0 + 8 * m][col] = h;
    sl[r0 + 8 * m][col] = (_Float16)(v - (float)h);
    part += fabsf(v);
  }
  if (cn_out) red[r0][col] = part;
  __syncthreads();
  if (cn_out && t < 32) {
    float ss = 0.f;
    #pragma unroll
    for (int q = 0; q < 8; ++q) ss += red[q][t];
    atomicAdd(&cn_out[(long)z * 128 + f0 + t], ss);
  }
  const int rr = t >> 3, cq = (t & 7) * 4;
  half4_t oh, ol;
  #pragma unroll
  for (int d = 0; d < 4; ++d) { oh[d] = sh[cq + d][rr]; ol[d] = sl[cq + d][rr]; }
  long ob = (long)z * 128 * N_NODES + (long)(f0 + rr) * N_NODES + j0 + cq;
  *(half4_t*)(TH + ob) = oh;
  *(half4_t*)(TL + ob) = ol;
}

// --- out[i][c*128+f] = relu( d*(T2sum*2^(i0+i1-33)) + d^2*sup + b ) --------
__global__ __launch_bounds__(256)
void final_k(const float4* __restrict__ T2, const float4* __restrict__ sup4,
             const float* __restrict__ dvec, const float* __restrict__ cn0,
             const float* __restrict__ cn1, const float* __restrict__ bias,
             float* __restrict__ out) {
  const int t = threadIdx.x;
  const int z = blockIdx.y;
  const int idx = blockIdx.x * 256 + t;
  const int i = idx >> 5;
  const int fq = (idx & 31) * 4;
  const long step4 = 4L * N_NODES * 32;
  long b4 = (long)z * N_NODES * 32 + idx;
  float4 s0 = T2[b4];
  float4 s1 = T2[b4 + step4];
  float4 s2 = T2[b4 + 2 * step4];
  float4 s3 = T2[b4 + 3 * step4];
  float4 su = sup4[idx];                     // sup[i][fq..fq+3]
  const float dn = dvec[(long)z * N_NODES + i];
  const float dn2 = dn * dn;
  float inv[4];
  #pragma unroll
  for (int d = 0; d < 4; ++d) {
    int i0 = ilogbf(fmaxf(cn0[(long)z * 128 + fq + d], 1e-37f));
    int i1 = ilogbf(fmaxf(cn1[(long)z * 128 + fq + d], 1e-37f));
    inv[d] = exp2f((float)(i0 + i1 - 33)) * dn;
  }
  float4 o;
  o.x = fmaxf(((s0.x + s1.x) + (s2.x + s3.x)) * inv[0] + dn2 * su.x + bias[fq + 0], 0.f);
  o.y = fmaxf(((s0.y + s1.y) + (s2.y + s3.y)) * inv[1] + dn2 * su.y + bias[fq + 1], 0.f);
  o.z = fmaxf(((s0.z + s1.z) + (s2.z + s3.z)) * inv[2] + dn2 * su.z + bias[fq + 2], 0.f);
  o.w = fmaxf(((s0.w + s1.w) + (s2.w + s3.w)) * inv[3] + dn2 * su.w + bias[fq + 3], 0.f);
  *(float4*)(out + (long)i * 512 + z * 128 + fq) = o;
}

extern "C" void kernel_launch(void* const* d_in, const int* in_sizes, int n_in,
                              void* d_out, int out_size, void* d_ws, size_t ws_size,
                              hipStream_t stream) {
  const float* A  = (const float*)d_in[0];
  const float* X  = (const float*)d_in[1];
  const float* w1 = (const float*)d_in[2];
  const float* w2 = (const float*)d_in[3];
  const float* w3 = (const float*)d_in[4];
  const float* gw = (const float*)d_in[5];
  const float* gb = (const float*)d_in[6];
  float* out = (float*)d_out;

  // ---- workspace layout (floats first, then f16 arena; all 16B aligned) ----
  float* ws   = (float*)d_ws;
  float* fw   = ws;                         // 64
  float* rc   = fw + 64;                    // 4*2048
  float* v1   = rc + 4 * N_NODES;           // 4*2048
  float* deg  = v1 + 4 * N_NODES;           // 4*2048
  float* dvec = deg + 4 * N_NODES;          // 4*2048
  float* sup  = dvec + 4 * N_NODES;         // 2048*128
  float* cn0  = sup + (long)N_NODES * 128;  // 512
  float* cn1  = cn0 + 512;                  // 512
  float* Mtmp = cn1 + 512;                  // [4kc][4ch][2048][128]
  _Float16* arena = (_Float16*)(Mtmp + 16L * N_NODES * 128);
  _Float16* VTH = arena;                    // [4][128][2048]
  _Float16* VTL = VTH + 4L * 128 * N_NODES;
  _Float16* T0H = VTL + 4L * 128 * N_NODES;
  _Float16* T0L = T0H + 4L * 128 * N_NODES;
  _Float16* T1H = T0L + 4L * 128 * N_NODES;
  _Float16* T1L = T1H + 4L * 128 * N_NODES;

  // ---- prework ----
  softmax3_zero_k<<<1, 256, 0, stream>>>(w1, w2, w3, fw, cn0);   // zeroes cn0+cn1
  support_k<<<N_NODES, 128, 0, stream>>>(X, gw, sup);
  // deg chain: rc = fw3-mix of rowsum(A_e); v1 = Hb@rc; deg = Ha@v1
  rc_from_A_k<<<N_NODES, 256, 0, stream>>>(A, fw, rc);
  matvecA_k<<<N_NODES, 256, 0, stream>>>(A, fw, 16, rc, v1);
  matvecA_k<<<N_NODES, 256, 0, stream>>>(A, fw, 0, v1, deg);
  // VT = (d .* sup * 2^13)^T split ; cn0 col 1-norms ; dvec
  transposeV_k<<<dim3(64, 4, 4), 256, 0, stream>>>(sup, deg, dvec,
                                                   VTH, VTL, cn0);
  // T0 = Hc @ VT   (mix-on-the-fly from A, fw offset 32)
  gemm_mix_k<<<1024, 256, 0, stream>>>(A, fw, 32, VTH, VTL, Mtmp);
  combineT_k<<<dim3(64, 4, 4), 256, 0, stream>>>(Mtmp, 4, cn0, cn1, T0H, T0L);
  // T1 = Hb @ T0'  (fw offset 16)
  gemm_mix_k<<<1024, 256, 0, stream>>>(A, fw, 16, T0H, T0L, Mtmp);
  combineT_k<<<dim3(64, 4, 4), 256, 0, stream>>>(Mtmp, 4, cn1, nullptr, T1H, T1L);
  // T2 = Ha @ T1'  (fw offset 0, fp32 partials)
  gemm_mix_k<<<1024, 256, 0, stream>>>(A, fw, 0, T1H, T1L, Mtmp);
  // out = relu( d*(T2*inv) + d^2*sup + b )
  final_k<<<dim3(256, 4), 256, 0, stream>>>((const float4*)Mtmp,
                                            (const float4*)sup, dvec,
                                            cn0, cn1, gb, out);
}

// Round 8
// 240.951 us; speedup vs baseline: 1.5080x; 1.1109x over previous
//
#include <hip/hip_runtime.h>
#include <math.h>

#define N_NODES 2048
#define NNE ((long)N_NODES * N_NODES)   // elems per channel matrix

// f16 two-term split: x ~= h + l (true residual). Three MFMA products
// (hh, lh, hl) into ONE fp32 accumulator; dropped l*l term ~2^-22 relative.
// Scale chain (all powers of 2, exact):
//   V0' = supd * 2^13
//   T0  = Hc@V0'  -> scaled by sT0[f] = 2^(10-ilogb(cn0[f])), cn0=sum_m|V0'|
//   T1  = Hb@T0'  -> scaled by sT1[f] = 2^(10-ilogb(cn1[f])), cn1=sum_j|T0'|
//   T2  = Ha@T1'  (fp32); out = d*(T2*2^(i0+i1-33)) + d^2*sup + b
// H matrices never materialized: gemm_mix_k mixes A->H on the fly.
// R8: cut LOGICAL bytes (every schedule variant converged at ~12 TB/s
//     logical service): 2 channels/block (A mixed once for both) + 64-row
//     tiles (halve B re-reads) -> 512->256 MB/stage. 8 waves, 128 KB LDS,
//     R7's counted-vmcnt schedule kept verbatim (same 8-VMEM/segment).
//     Deg chain: serpentine traversal (v1 pass reversed) for L3 tail reuse.
#define SUPD_SCALE 8192.0f

typedef _Float16 half4_t __attribute__((ext_vector_type(4)));
typedef _Float16 half8_t __attribute__((ext_vector_type(8)));
typedef float    floatx4 __attribute__((ext_vector_type(4)));

__device__ __forceinline__ void async_cp16(const void* g, void* l) {
  __builtin_amdgcn_global_load_lds((const __attribute__((address_space(1))) void*)g,
                                   (__attribute__((address_space(3))) void*)l,
                                   16, 0, 0);
}

__device__ __forceinline__ float colscale_from(float cn) {
  return exp2f((float)(10 - ilogbf(fmaxf(cn, 1e-37f))));
}

// ---- softmax of the three 4x4 weight matrices + zero cn0/cn1 (1024 f) ----
__global__ void softmax3_zero_k(const float* __restrict__ w1,
                                const float* __restrict__ w2,
                                const float* __restrict__ w3,
                                float* __restrict__ fw,
                                float* __restrict__ cn) {
  int t = threadIdx.x;
  float4 z4 = {0.f, 0.f, 0.f, 0.f};
  ((float4*)cn)[t] = z4;                       // 256*4 = 1024 floats
  if (t < 12) {
    const float* src = (t < 4) ? w1 : (t < 8) ? w2 : w3;
    int r = t & 3;
    float v0 = src[r * 4 + 0], v1 = src[r * 4 + 1];
    float v2 = src[r * 4 + 2], v3 = src[r * 4 + 3];
    float m = fmaxf(fmaxf(v0, v1), fmaxf(v2, v3));
    float e0 = expf(v0 - m), e1 = expf(v1 - m), e2 = expf(v2 - m), e3 = expf(v3 - m);
    float inv = 1.0f / (e0 + e1 + e2 + e3);
    fw[t * 4 + 0] = e0 * inv; fw[t * 4 + 1] = e1 * inv;
    fw[t * 4 + 2] = e2 * inv; fw[t * 4 + 3] = e3 * inv;
  }
}

// ---------------- support = X @ gcn_w  [2048,256]@[256,128] ----------------
__global__ __launch_bounds__(128)
void support_k(const float* __restrict__ X, const float* __restrict__ W,
               float* __restrict__ sup) {
  __shared__ float Xs[256];
  const int t = threadIdx.x;
  const int m = blockIdx.x;
  Xs[t]       = X[(long)m * 256 + t];
  Xs[t + 128] = X[(long)m * 256 + t + 128];
  __syncthreads();
  float acc = 0.f;
  #pragma unroll 8
  for (int k = 0; k < 256; ++k) acc = fmaf(Xs[k], W[(long)k * 128 + t], acc);
  sup[(long)m * 128 + t] = acc;
}

// ---- rc[c][r] = sum_e fw3[c][e] * rowsum(A_e)[r] ----------
__global__ __launch_bounds__(256)
void rc_from_A_k(const float* __restrict__ A, const float* __restrict__ fw,
                 float* __restrict__ rc) {
  __shared__ float red[4][4];
  const int r = blockIdx.x;
  const int w = threadIdx.x >> 6, lane = threadIdx.x & 63;
  float se[4];
  #pragma unroll
  for (int e = 0; e < 4; ++e) {
    const float4* row = (const float4*)(A + (long)e * NNE + (long)r * N_NODES);
    float s = 0.f;
    #pragma unroll
    for (int q = 0; q < 2; ++q) {
      float4 a = row[w * 128 + q * 64 + lane];
      s += (a.x + a.y) + (a.z + a.w);
    }
    se[e] = s;
  }
  float m[4];
  #pragma unroll
  for (int c = 0; c < 4; ++c)
    m[c] = fw[32 + c * 4 + 0] * se[0] + fw[32 + c * 4 + 1] * se[1] +
           fw[32 + c * 4 + 2] * se[2] + fw[32 + c * 4 + 3] * se[3];
  #pragma unroll
  for (int o = 32; o > 0; o >>= 1) {
    #pragma unroll
    for (int c = 0; c < 4; ++c) m[c] += __shfl_down(m[c], o, 64);
  }
  if (lane == 0) {
    #pragma unroll
    for (int c = 0; c < 4; ++c) red[w][c] = m[c];
  }
  __syncthreads();
  if (threadIdx.x < 4) {
    int c = threadIdx.x;
    rc[c * N_NODES + r] = (red[0][c] + red[1][c]) + (red[2][c] + red[3][c]);
  }
}

// -- vout[c][r] = sum_e fw[off+c*4+e] * (A_e @ vin[c])[r]  (fp32) ----------
// rev=1 traverses rows in reverse (serpentine L3 reuse across passes).
__global__ __launch_bounds__(256)
void matvecA_k(const float* __restrict__ A, const float* __restrict__ fw, int off,
               const float* __restrict__ vin, float* __restrict__ vout, int rev) {
  __shared__ float red[4][4];
  const int r = rev ? (N_NODES - 1 - blockIdx.x) : blockIdx.x;
  const int w = threadIdx.x >> 6, lane = threadIdx.x & 63;
  float acc[4][4] = {{0.f}};
  #pragma unroll
  for (int q = 0; q < 2; ++q) {
    const int j4 = w * 128 + q * 64 + lane;
    float4 v0 = *(const float4*)&vin[0 * 2048 + j4 * 4];
    float4 v1 = *(const float4*)&vin[1 * 2048 + j4 * 4];
    float4 v2 = *(const float4*)&vin[2 * 2048 + j4 * 4];
    float4 v3 = *(const float4*)&vin[3 * 2048 + j4 * 4];
    #pragma unroll
    for (int e = 0; e < 4; ++e) {
      float4 a = *(const float4*)(A + (long)e * NNE + (long)r * N_NODES + j4 * 4);
      acc[e][0] += (a.x * v0.x + a.y * v0.y) + (a.z * v0.z + a.w * v0.w);
      acc[e][1] += (a.x * v1.x + a.y * v1.y) + (a.z * v1.z + a.w * v1.w);
      acc[e][2] += (a.x * v2.x + a.y * v2.y) + (a.z * v2.z + a.w * v2.w);
      acc[e][3] += (a.x * v3.x + a.y * v3.y) + (a.z * v3.z + a.w * v3.w);
    }
  }
  float m[4];
  #pragma unroll
  for (int c = 0; c < 4; ++c)
    m[c] = fw[off + c * 4 + 0] * acc[0][c] + fw[off + c * 4 + 1] * acc[1][c] +
           fw[off + c * 4 + 2] * acc[2][c] + fw[off + c * 4 + 3] * acc[3][c];
  #pragma unroll
  for (int o = 32; o > 0; o >>= 1) {
    #pragma unroll
    for (int c = 0; c < 4; ++c) m[c] += __shfl_down(m[c], o, 64);
  }
  if (lane == 0) {
    #pragma unroll
    for (int c = 0; c < 4; ++c) red[w][c] = m[c];
  }
  __syncthreads();
  if (threadIdx.x < 4) {
    int c = threadIdx.x;
    vout[c * N_NODES + r] = (red[0][c] + red[1][c]) + (red[2][c] + red[3][c]);
  }
}

// -- fused: dm = 1/sqrt(1+deg); dvec side output;
// -- VT[z][f][m] = split( dm*sup*2^13 ); cn0[z][f] += sum_m |val| ----------
__global__ __launch_bounds__(256)
void transposeV_k(const float* __restrict__ sup, const float* __restrict__ deg,
                  float* __restrict__ dvec,
                  _Float16* __restrict__ TH, _Float16* __restrict__ TL,
                  float* __restrict__ cn0) {
  __shared__ _Float16 sh[32][33], sl[32][33];
  __shared__ float red[8][32];
  const int t = threadIdx.x;
  const int z = blockIdx.z;
  const int m0 = blockIdx.x * 32, f0 = blockIdx.y * 32;
  const int r0 = t >> 5, col = t & 31;
  float part = 0.f;
  #pragma unroll
  for (int m = 0; m < 4; ++m) {
    const int row = m0 + r0 + 8 * m;
    float dm = 1.0f / sqrtf(1.0f + deg[(long)z * N_NODES + row]);
    float sv = sup[(long)row * 128 + f0 + col] * dm;
    if (blockIdx.y == 0 && col == 0) dvec[(long)z * N_NODES + row] = dm;
    float v = sv * SUPD_SCALE;
    _Float16 h = (_Float16)v;
    sh[r0 + 8 * m][col] = h;
    sl[r0 + 8 * m][col] = (_Float16)(v - (float)h);
    part += fabsf(v);
  }
  red[r0][col] = part;
  __syncthreads();
  if (t < 32) {
    float s = 0.f;
    #pragma unroll
    for (int q = 0; q < 8; ++q) s += red[q][t];
    atomicAdd(&cn0[(long)z * 128 + f0 + t], s);
  }
  const int rr = t >> 3, cq = (t & 7) * 4;
  half4_t oh, ol;
  #pragma unroll
  for (int d = 0; d < 4; ++d) { oh[d] = sh[cq + d][rr]; ol[d] = sl[cq + d][rr]; }
  long ob = (long)z * 128 * N_NODES + (long)(f0 + rr) * N_NODES + m0 + cq;
  *(half4_t*)(TH + ob) = oh;
  *(half4_t*)(TL + ob) = ol;
}

// ---- fused mix+GEMM: partials[kc][ch][i][f] = (sum_e fw[off+ch*4+e] A_e) @ B[ch]
// TWO channels per block (A staged+mixed once for both), 64-row tiles.
// Flat grid 256 = tile(32) + 32*chpair(2) + 64*kc(4): entire grid
// co-resident (1 block/CU, 8 waves); A-sharers of a tile same-XCD.
// Counted-vmcnt pipeline identical to R7 (8 VMEM ops per segment per
// thread: 4 A dwordx4 + 4 B cp16; barrier keeps newest 8 in flight).
__global__ __launch_bounds__(512, 1)
void gemm_mix_k(const float* __restrict__ A, const float* __restrict__ fw, int off,
                const _Float16* __restrict__ BH, const _Float16* __restrict__ BL,
                float* __restrict__ C) {
  __shared__ __align__(16) _Float16 BsArr[3 * 16384]; // 3 bufs x [2ch][2pl][128f][32k]
  __shared__ __align__(16) _Float16 HsArr[2 * 8192];  // 2 bufs x [2ch][2pl][64r][32k]

  const int t = threadIdx.x;
  const int lane = t & 63;
  const int w = t >> 6;                 // 0..7
  const int bid = blockIdx.x;
  const int tile = bid & 31;
  const int chp = (bid >> 5) & 1;
  const int kc = bid >> 6;              // 0..3
  const int i0 = tile * 64;
  const int ch0 = chp * 2;
  const long koff = (long)kc * 512;

  float wv0[4], wv1[4];
  #pragma unroll
  for (int e = 0; e < 4; ++e) {
    wv0[e] = fw[off + ch0 * 4 + e];
    wv1[e] = fw[off + (ch0 + 1) * 4 + e];
  }

  // A per-thread source: row rr (0..63), k-cols k4..k4+3, all 4 e
  const int rr = t >> 3;
  const int k4 = (t & 7) * 4;
  const float* gA = A + (long)(i0 + rr) * N_NODES + koff + k4;
  // H store offset in a [64r][32k] plane, k-group swizzle p=(g+(row>>1))&3
  const int hoff = rr * 32 + (((k4 >> 3) + (rr >> 1)) & 3) * 8 + (k4 & 7);

  // B staging role: wave w -> (ch = w>>2, plane = (w>>1)&1, half64 = w&1)
  const int sch = w >> 2, spl = (w >> 1) & 1, shalf = w & 1;
  const int kc_st = (((lane & 3) - ((lane >> 3) & 3)) & 3) * 8;
  const _Float16* gB = (spl ? BL : BH)
      + ((long)(ch0 + sch) * 128 + shalf * 64 + (lane >> 2)) * (long)N_NODES
      + koff + kc_st;
  const int sdst = sch * 8192 + spl * 4096 + shalf * 2048;

  // MFMA fragment offsets: wm = 16-row strip (0..3), wn = 64-col half (0..1)
  const int wm = w >> 1;
  const int wn = w & 1;
  const int fr = lane & 15;
  const int fq = lane >> 4;
  const int fkz = ((fq + (fr >> 1)) & 3) * 8;
  const int aoff = (wm * 16 + fr) * 32 + fkz;

  floatx4 acc[2][4];
  #pragma unroll
  for (int c = 0; c < 2; ++c)
    #pragma unroll
    for (int j = 0; j < 4; ++j) {
      floatx4 zz4 = {0.f, 0.f, 0.f, 0.f};
      acc[c][j] = zz4;
    }

  float4 sA[4], sB[4], sC[4];           // 3 named A register sets

  auto loadA = [&](float4* av, int kt) {
    const float* g = gA + kt * 32;
    av[0] = *(const float4*)(g);
    av[1] = *(const float4*)(g + NNE);
    av[2] = *(const float4*)(g + 2 * NNE);
    av[3] = *(const float4*)(g + 3 * NNE);
  };
  auto stageB = [&](int buf, int kt) {
    _Float16* lb = BsArr + buf * 16384 + sdst;
    const _Float16* g = gB + kt * 32;
    #pragma unroll
    for (int q = 0; q < 4; ++q)
      async_cp16(g + (long)q * (16L * N_NODES), lb + q * 512 + lane * 8);
  };
  auto mixStore = [&](const float4* av, int hb) {
    half4_t h0, l0, h1, l1;
    #pragma unroll
    for (int d = 0; d < 4; ++d) {
      float a0 = ((const float*)&av[0])[d], a1 = ((const float*)&av[1])[d];
      float a2 = ((const float*)&av[2])[d], a3 = ((const float*)&av[3])[d];
      float o0 = wv0[0] * a0 + wv0[1] * a1 + wv0[2] * a2 + wv0[3] * a3;
      float o1 = wv1[0] * a0 + wv1[1] * a1 + wv1[2] * a2 + wv1[3] * a3;
      _Float16 hh0 = (_Float16)o0, hh1 = (_Float16)o1;
      h0[d] = hh0; l0[d] = (_Float16)(o0 - (float)hh0);
      h1[d] = hh1; l1[d] = (_Float16)(o1 - (float)hh1);
    }
    _Float16* hb0 = HsArr + hb * 8192;
    *(half4_t*)&hb0[hoff] = h0;
    *(half4_t*)&hb0[2048 + hoff] = l0;
    *(half4_t*)&hb0[4096 + hoff] = h1;
    *(half4_t*)&hb0[6144 + hoff] = l1;
  };
  auto domfma = [&](int buf, int hb) {
    const _Float16* hbse = HsArr + hb * 8192;
    const _Float16* bbse = BsArr + buf * 16384;
    #pragma unroll
    for (int c = 0; c < 2; ++c) {
      half8_t ah = *(const half8_t*)&hbse[c * 4096 + aoff];
      half8_t al = *(const half8_t*)&hbse[c * 4096 + 2048 + aoff];
      #pragma unroll
      for (int nt = 0; nt < 4; ++nt) {
        const int bo = c * 8192 + (wn * 64 + nt * 16 + fr) * 32 + fkz;
        half8_t bh = *(const half8_t*)&bbse[bo];
        half8_t bl = *(const half8_t*)&bbse[bo + 4096];
        acc[c][nt] = __builtin_amdgcn_mfma_f32_16x16x32_f16(ah, bh, acc[c][nt], 0, 0, 0);
        acc[c][nt] = __builtin_amdgcn_mfma_f32_16x16x32_f16(al, bh, acc[c][nt], 0, 0, 0);
        acc[c][nt] = __builtin_amdgcn_mfma_f32_16x16x32_f16(ah, bl, acc[c][nt], 0, 0, 0);
      }
    }
  };

#define SB0 __builtin_amdgcn_sched_barrier(0)
#define BAR_V8  do { SB0; asm volatile("s_waitcnt vmcnt(8) lgkmcnt(0)" ::: "memory"); \
                     SB0; __builtin_amdgcn_s_barrier(); SB0; } while (0)
#define BAR_V4  do { SB0; asm volatile("s_waitcnt vmcnt(4) lgkmcnt(0)" ::: "memory"); \
                     SB0; __builtin_amdgcn_s_barrier(); SB0; } while (0)

#define SEGMENT(KT, PA, PM, BUFS, BUFM)                                       \
  do {                                                                        \
    if ((KT) + 3 < 16) loadA(PA, (KT) + 3);                                   \
    if ((KT) + 2 < 16) stageB(BUFS, (KT) + 2);                                \
    domfma(BUFM, (KT) & 1);                                                   \
    if ((KT) + 1 < 16) mixStore(PM, ((KT) + 1) & 1);                          \
    if ((KT) <= 12)      BAR_V8;                                              \
    else if ((KT) == 13) BAR_V4;                                              \
    else if ((KT) == 14) __syncthreads();                                     \
  } while (0)

  // prologue: A(0..2) -> sA/sB/sC; B chunks 0,1 -> bufs 0,1; H(0) -> Hs[0]
  loadA(sA, 0); loadA(sB, 1); loadA(sC, 2);
  stageB(0, 0); stageB(1, 1);
  mixStore(sA, 0);
  BAR_V4;   // drains chunk0's cp16 (+A loads); chunk1's 4 cp16 stay in flight

  SEGMENT(0,  sA, sB, 2, 0);
  SEGMENT(1,  sB, sC, 0, 1);
  SEGMENT(2,  sC, sA, 1, 2);
  SEGMENT(3,  sA, sB, 2, 0);
  SEGMENT(4,  sB, sC, 0, 1);
  SEGMENT(5,  sC, sA, 1, 2);
  SEGMENT(6,  sA, sB, 2, 0);
  SEGMENT(7,  sB, sC, 0, 1);
  SEGMENT(8,  sC, sA, 1, 2);
  SEGMENT(9,  sA, sB, 2, 0);
  SEGMENT(10, sB, sC, 0, 1);
  SEGMENT(11, sC, sA, 1, 2);
  SEGMENT(12, sA, sB, 2, 0);
  SEGMENT(13, sB, sC, 0, 1);
  SEGMENT(14, sC, sA, 1, 2);
  SEGMENT(15, sA, sB, 2, 0);

#undef SEGMENT
#undef BAR_V8
#undef BAR_V4
#undef SB0

  const int er = fq * 4;
  const int ec = lane & 15;
  #pragma unroll
  for (int c = 0; c < 2; ++c) {
    float* Cb = C + ((long)(kc * 4 + ch0 + c) * N_NODES + i0 + wm * 16) * 128;
    #pragma unroll
    for (int nt = 0; nt < 4; ++nt) {
      const int f = wn * 64 + nt * 16 + ec;
      #pragma unroll
      for (int r = 0; r < 4; ++r)
        Cb[(long)(er + r) * 128 + f] = acc[c][nt][r];
    }
  }
}

// -- T'[z][f][j] = split( (sum_parts P[pp][z][j][f]) * s(cn_in[z][f]) ) -----
__global__ __launch_bounds__(256)
void combineT_k(const float* __restrict__ P, int parts,
                const float* __restrict__ cn_in, float* __restrict__ cn_out,
                _Float16* __restrict__ TH, _Float16* __restrict__ TL) {
  __shared__ _Float16 sh[32][33], sl[32][33];
  __shared__ float red[8][32];
  const int t = threadIdx.x;
  const int z = blockIdx.z;
  const int j0 = blockIdx.x * 32, f0 = blockIdx.y * 32;
  const int r0 = t >> 5, col = t & 31;
  const float s = colscale_from(cn_in[(long)z * 128 + f0 + col]);
  const long step = 4L * N_NODES * 128;
  float part = 0.f;
  #pragma unroll
  for (int m = 0; m < 4; ++m) {
    long idx = ((long)z * N_NODES + j0 + r0 + 8 * m) * 128 + f0 + col;
    float v = (P[idx] + P[idx + step]) + (P[idx + 2 * step] + P[idx + 3 * step]);
    v *= s;
    _Float16 h = (_Float16)v;
    sh[r0 + 8 * m][col] = h;
    sl[r0 + 8 * m][col] = (_Float16)(v - (float)h);
    part += fabsf(v);
  }
  if (cn_out) red[r0][col] = part;
  __syncthreads();
  if (cn_out && t < 32) {
    float ss = 0.f;
    #pragma unroll
    for (int q = 0; q < 8; ++q) ss += red[q][t];
    atomicAdd(&cn_out[(long)z * 128 + f0 + t], ss);
  }
  const int rr = t >> 3, cq = (t & 7) * 4;
  half4_t oh, ol;
  #pragma unroll
  for (int d = 0; d < 4; ++d) { oh[d] = sh[cq + d][rr]; ol[d] = sl[cq + d][rr]; }
  long ob = (long)z * 128 * N_NODES + (long)(f0 + rr) * N_NODES + j0 + cq;
  *(half4_t*)(TH + ob) = oh;
  *(half4_t*)(TL + ob) = ol;
}

// --- out[i][c*128+f] = relu( d*(T2sum*2^(i0+i1-33)) + d^2*sup + b ) --------
__global__ __launch_bounds__(256)
void final_k(const float4* __restrict__ T2, const float4* __restrict__ sup4,
             const float* __restrict__ dvec, const float* __restrict__ cn0,
             const float* __restrict__ cn1, const float* __restrict__ bias,
             float* __restrict__ out) {
  const int t = threadIdx.x;
  const int z = blockIdx.y;
  const int idx = blockIdx.x * 256 + t;
  const int i = idx >> 5;
  const int fq = (idx & 31) * 4;
  const long step4 = 4L * N_NODES * 32;
  long b4 = (long)z * N_NODES * 32 + idx;
  float4 s0 = T2[b4];
  float4 s1 = T2[b4 + step4];
  float4 s2 = T2[b4 + 2 * step4];
  float4 s3 = T2[b4 + 3 * step4];
  float4 su = sup4[idx];                     // sup[i][fq..fq+3]
  const float dn = dvec[(long)z * N_NODES + i];
  const float dn2 = dn * dn;
  float inv[4];
  #pragma unroll
  for (int d = 0; d < 4; ++d) {
    int i0 = ilogbf(fmaxf(cn0[(long)z * 128 + fq + d], 1e-37f));
    int i1 = ilogbf(fmaxf(cn1[(long)z * 128 + fq + d], 1e-37f));
    inv[d] = exp2f((float)(i0 + i1 - 33)) * dn;
  }
  float4 o;
  o.x = fmaxf(((s0.x + s1.x) + (s2.x + s3.x)) * inv[0] + dn2 * su.x + bias[fq + 0], 0.f);
  o.y = fmaxf(((s0.y + s1.y) + (s2.y + s3.y)) * inv[1] + dn2 * su.y + bias[fq + 1], 0.f);
  o.z = fmaxf(((s0.z + s1.z) + (s2.z + s3.z)) * inv[2] + dn2 * su.z + bias[fq + 2], 0.f);
  o.w = fmaxf(((s0.w + s1.w) + (s2.w + s3.w)) * inv[3] + dn2 * su.w + bias[fq + 3], 0.f);
  *(float4*)(out + (long)i * 512 + z * 128 + fq) = o;
}

extern "C" void kernel_launch(void* const* d_in, const int* in_sizes, int n_in,
                              void* d_out, int out_size, void* d_ws, size_t ws_size,
                              hipStream_t stream) {
  const float* A  = (const float*)d_in[0];
  const float* X  = (const float*)d_in[1];
  const float* w1 = (const float*)d_in[2];
  const float* w2 = (const float*)d_in[3];
  const float* w3 = (const float*)d_in[4];
  const float* gw = (const float*)d_in[5];
  const float* gb = (const float*)d_in[6];
  float* out = (float*)d_out;

  // ---- workspace layout (floats first, then f16 arena; all 16B aligned) ----
  float* ws   = (float*)d_ws;
  float* fw   = ws;                         // 64
  float* rc   = fw + 64;                    // 4*2048
  float* v1   = rc + 4 * N_NODES;           // 4*2048
  float* deg  = v1 + 4 * N_NODES;           // 4*2048
  float* dvec = deg + 4 * N_NODES;          // 4*2048
  float* sup  = dvec + 4 * N_NODES;         // 2048*128
  float* cn0  = sup + (long)N_NODES * 128;  // 512
  float* cn1  = cn0 + 512;                  // 512
  float* Mtmp = cn1 + 512;                  // [4kc][4ch][2048][128]
  _Float16* arena = (_Float16*)(Mtmp + 16L * N_NODES * 128);
  _Float16* VTH = arena;                    // [4][128][2048]
  _Float16* VTL = VTH + 4L * 128 * N_NODES;
  _Float16* T0H = VTL + 4L * 128 * N_NODES;
  _Float16* T0L = T0H + 4L * 128 * N_NODES;
  _Float16* T1H = T0L + 4L * 128 * N_NODES;
  _Float16* T1L = T1H + 4L * 128 * N_NODES;

  // ---- prework ----
  softmax3_zero_k<<<1, 256, 0, stream>>>(w1, w2, w3, fw, cn0);   // zeroes cn0+cn1
  support_k<<<N_NODES, 128, 0, stream>>>(X, gw, sup);
  // deg chain: rc = fw3-mix of rowsum(A_e); v1 = Hb@rc (reverse traversal,
  // L3 tail reuse); deg = Ha@v1 (forward, starts where v1 pass ended)
  rc_from_A_k<<<N_NODES, 256, 0, stream>>>(A, fw, rc);
  matvecA_k<<<N_NODES, 256, 0, stream>>>(A, fw, 16, rc, v1, 1);
  matvecA_k<<<N_NODES, 256, 0, stream>>>(A, fw, 0, v1, deg, 0);
  // VT = (d .* sup * 2^13)^T split ; cn0 col 1-norms ; dvec
  transposeV_k<<<dim3(64, 4, 4), 256, 0, stream>>>(sup, deg, dvec,
                                                   VTH, VTL, cn0);
  // T0 = Hc @ VT   (mix-on-the-fly from A, fw offset 32)
  gemm_mix_k<<<256, 512, 0, stream>>>(A, fw, 32, VTH, VTL, Mtmp);
  combineT_k<<<dim3(64, 4, 4), 256, 0, stream>>>(Mtmp, 4, cn0, cn1, T0H, T0L);
  // T1 = Hb @ T0'  (fw offset 16)
  gemm_mix_k<<<256, 512, 0, stream>>>(A, fw, 16, T0H, T0L, Mtmp);
  combineT_k<<<dim3(64, 4, 4), 256, 0, stream>>>(Mtmp, 4, cn1, nullptr, T1H, T1L);
  // T2 = Ha @ T1'  (fw offset 0, fp32 partials)
  gemm_mix_k<<<256, 512, 0, stream>>>(A, fw, 0, T1H, T1L, Mtmp);
  // out = relu( d*(T2*inv) + d^2*sup + b )
  final_k<<<dim3(256, 4), 256, 0, stream>>>((const float4*)Mtmp,
                                            (const float4*)sup, dvec,
                                            cn0, cn1, gb, out);
}